// Round 1
// baseline (1591.944 us; speedup 1.0000x reference)
//
#include <hip/hip_runtime.h>

#define N_NODES 100000
#define N_CH 16
#define DIM 3
#define N_EDGES 1600000
#define N_STEPS 2
#define FP32_EPS 1.1920929e-7f

// ---------------------------------------------------------------------------
// deg[i] = sum of weights over edges with sender i  (step-invariant)
// ---------------------------------------------------------------------------
__global__ void deg_kernel(const int* __restrict__ senders,
                           const float* __restrict__ weights,
                           float* __restrict__ deg) {
    int e = blockIdx.x * blockDim.x + threadIdx.x;
    if (e < N_EDGES) {
        atomicAdd(&deg[senders[e]], weights[e]);
    }
}

// ---------------------------------------------------------------------------
// For each (edge, channel): logs = sphere_log(x[s], x[r]) * w, scatter-add
// into agg[s].  One thread per (edge, channel); c = tid & 15 so the 16
// channels of an edge are consecutive lanes (coalesced 192B per edge).
// ---------------------------------------------------------------------------
__global__ void edge_kernel(const float* __restrict__ x,
                            const int* __restrict__ senders,
                            const int* __restrict__ receivers,
                            const float* __restrict__ weights,
                            float* __restrict__ agg) {
    unsigned int tid = blockIdx.x * blockDim.x + threadIdx.x;
    if (tid >= (unsigned int)N_EDGES * N_CH) return;
    unsigned int e = tid >> 4;
    unsigned int c = tid & 15u;

    int s = senders[e];
    int r = receivers[e];
    float w = weights[e];

    const float* xs = x + ((size_t)s * N_CH + c) * DIM;
    const float* xr = x + ((size_t)r * N_CH + c) * DIM;
    float ax = xs[0], ay = xs[1], az = xs[2];
    float bx = xr[0], by = xr[1], bz = xr[2];

    float cd = ax * bx + ay * by + az * bz;
    cd = fminf(fmaxf(cd, -1.0f + 1e-7f), 1.0f - 1e-7f);
    float theta = acosf(cd);
    // sin(arccos(c)) == sqrt(1-c^2); clamp keeps it >= ~4.5e-4
    float sn = sqrtf(fmaxf(1.0f - cd * cd, 0.0f));
    float f = w * theta / sn;

    float lx = f * (bx - cd * ax);
    float ly = f * (by - cd * ay);
    float lz = f * (bz - cd * az);

    float* ag = agg + ((size_t)s * N_CH + c) * DIM;
    atomicAdd(&ag[0], lx);
    atomicAdd(&ag[1], ly);
    atomicAdd(&ag[2], lz);
}

// ---------------------------------------------------------------------------
// Per (node, channel): v = -agg/deg ; gate ; x_new = sphere_exp(x, v_final)
// v_final = -(v * scale) * t = (agg/deg) * scale * t
// ---------------------------------------------------------------------------
__global__ void node_kernel(const float* __restrict__ xin,
                            const float* __restrict__ agg,
                            const float* __restrict__ deg,
                            const float* __restrict__ t_sqrt,
                            const float* __restrict__ alpha_sqrt,
                            const float* __restrict__ beta_sqrt,
                            float* __restrict__ xout) {
    unsigned int tid = blockIdx.x * blockDim.x + threadIdx.x;
    if (tid >= (unsigned int)N_NODES * N_CH) return;
    unsigned int i = tid >> 4;
    unsigned int c = tid & 15u;

    float dg = deg[i] + 1e-12f;

    const float* ag = agg + (size_t)tid * DIM;
    // v = L(x) = -agg/deg
    float vx = -ag[0] / dg;
    float vy = -ag[1] / dg;
    float vz = -ag[2] / dg;

    float t = t_sqrt[c]; t = (t * t) * (1.0f / N_STEPS);
    float a = alpha_sqrt[c]; a = a * a;
    float b = beta_sqrt[c]; b = b * b;

    float nrm = sqrtf(vx * vx + vy * vy + vz * vz + FP32_EPS);
    float d = 1.0f / (1.0f + __expf(-b * (nrm - a)));
    float scale = (nrm * d <= 1.0f) ? d : (1.0f / nrm);
    float fs = -scale * t;   // v_final = v * (-scale * t)
    vx *= fs; vy *= fs; vz *= fs;

    const float* xi = xin + (size_t)tid * DIM;
    float ax = xi[0], ay = xi[1], az = xi[2];

    float n = sqrtf(vx * vx + vy * vy + vz * vz + 1e-16f);
    float cn = cosf(n);
    float sf = sinf(n) / n;

    float* xo = xout + (size_t)tid * DIM;
    xo[0] = cn * ax + sf * vx;
    xo[1] = cn * ay + sf * vy;
    xo[2] = cn * az + sf * vz;
}

extern "C" void kernel_launch(void* const* d_in, const int* in_sizes, int n_in,
                              void* d_out, int out_size, void* d_ws, size_t ws_size,
                              hipStream_t stream) {
    const float* nodes      = (const float*)d_in[0];
    const int*   senders    = (const int*)d_in[1];
    const int*   receivers  = (const int*)d_in[2];
    const float* weights    = (const float*)d_in[3];
    const float* t_sqrt     = (const float*)d_in[4];
    const float* alpha_sqrt = (const float*)d_in[5];
    const float* beta_sqrt  = (const float*)d_in[6];
    float* out = (float*)d_out;

    float* agg = (float*)d_ws;                                   // N*C*D floats
    float* deg = agg + (size_t)N_NODES * N_CH * DIM;             // N floats

    // degree (step-invariant)
    hipMemsetAsync(deg, 0, N_NODES * sizeof(float), stream);
    deg_kernel<<<(N_EDGES + 255) / 256, 256, 0, stream>>>(senders, weights, deg);

    const float* xin = nodes;
    for (int step = 0; step < N_STEPS; ++step) {
        hipMemsetAsync(agg, 0, (size_t)N_NODES * N_CH * DIM * sizeof(float), stream);
        unsigned int n_ec = (unsigned int)N_EDGES * N_CH;
        edge_kernel<<<(n_ec + 255) / 256, 256, 0, stream>>>(xin, senders, receivers,
                                                            weights, agg);
        unsigned int n_nc = (unsigned int)N_NODES * N_CH;
        node_kernel<<<(n_nc + 255) / 256, 256, 0, stream>>>(xin, agg, deg, t_sqrt,
                                                            alpha_sqrt, beta_sqrt, out);
        xin = out;
    }
}

// Round 4
// 725.885 us; speedup vs baseline: 2.1931x; 2.1931x over previous
//
#include <hip/hip_runtime.h>

#define N_NODES 100000
#define N_CH 16
#define DIM 3
#define N_EDGES 1600000
#define N_STEPS 2
// float32 machine eps (the reference wraps it in jnp.float32; exact value)
#define EPS_D 1.1920928955078125e-7

#define SCAN_BLOCK 1024

// ===========================================================================
// CSR build: histogram -> exclusive scan -> scatter edge payloads
// ===========================================================================
__global__ void hist_kernel(const int* __restrict__ senders,
                            int* __restrict__ cnt) {
    int e = blockIdx.x * blockDim.x + threadIdx.x;
    if (e < N_EDGES) atomicAdd(&cnt[senders[e]], 1);
}

__global__ void scan_kernel(const int* __restrict__ cnt,
                            int* __restrict__ rowptr) {
    __shared__ int sdata[SCAN_BLOCK];
    const int ITEMS = (N_NODES + SCAN_BLOCK - 1) / SCAN_BLOCK;  // 98
    int t = threadIdx.x;
    int base = t * ITEMS;
    int local = 0;
    for (int k = 0; k < ITEMS; ++k) {
        int idx = base + k;
        if (idx < N_NODES) local += cnt[idx];
    }
    sdata[t] = local;
    __syncthreads();
    for (int off = 1; off < SCAN_BLOCK; off <<= 1) {
        int v = (t >= off) ? sdata[t - off] : 0;
        __syncthreads();
        sdata[t] += v;
        __syncthreads();
    }
    int run = (t == 0) ? 0 : sdata[t - 1];
    for (int k = 0; k < ITEMS; ++k) {
        int idx = base + k;
        if (idx < N_NODES) {
            rowptr[idx] = run;
            run += cnt[idx];
        }
    }
    if (t == SCAN_BLOCK - 1) rowptr[N_NODES] = sdata[SCAN_BLOCK - 1];
}

__global__ void scatter_kernel(const int* __restrict__ senders,
                               const int* __restrict__ receivers,
                               const float* __restrict__ weights,
                               const int* __restrict__ rowptr,
                               int* __restrict__ fill,
                               int* __restrict__ cols,
                               float* __restrict__ wv) {
    int e = blockIdx.x * blockDim.x + threadIdx.x;
    if (e >= N_EDGES) return;
    int s = senders[e];
    int pos = rowptr[s] + atomicAdd(&fill[s], 1);
    cols[pos] = receivers[e];
    wv[pos] = weights[e];
}

// ===========================================================================
// Fused flow step, full fp64 (TI = float for step 1, double for step 2;
// TO = double for step 1, float for final step). One wave64 per node,
// lane = c + 16*j (c = channel, j = edge slice).
// ===========================================================================
template <typename TI, typename TO>
__global__ void flow_kernel(const TI* __restrict__ x,
                            const int* __restrict__ rowptr,
                            const int* __restrict__ cols,
                            const float* __restrict__ wv,
                            const float* __restrict__ t_sqrt,
                            const float* __restrict__ alpha_sqrt,
                            const float* __restrict__ beta_sqrt,
                            TO* __restrict__ xout) {
    int wave = threadIdx.x >> 6;                 // 4 waves / block
    int lane = threadIdx.x & 63;
    int i = blockIdx.x * 4 + wave;
    if (i >= N_NODES) return;
    int c = lane & 15;
    int j = lane >> 4;

    int beg = rowptr[i];
    int end = rowptr[i + 1];

    const TI* xi = x + ((size_t)i * N_CH + c) * DIM;
    double ax = (double)xi[0], ay = (double)xi[1], az = (double)xi[2];

    double sx = 0.0, sy = 0.0, sz = 0.0, sw = 0.0;
    for (int k = beg + j; k < end; k += 4) {
        int r = cols[k];
        double w = (double)wv[k];
        const TI* xr = x + ((size_t)r * N_CH + c) * DIM;
        double bx = (double)xr[0], by = (double)xr[1], bz = (double)xr[2];

        double cd = ax * bx + ay * by + az * bz;
        cd = fmin(fmax(cd, -1.0 + 1e-7), 1.0 - 1e-7);
        double theta = acos(cd);
        double sn = sqrt(1.0 - cd * cd);         // == sin(acos(cd)) to ~1e-16
        double f = w * theta / sn;

        sx += f * (bx - cd * ax);
        sy += f * (by - cd * ay);
        sz += f * (bz - cd * az);
        sw += w;
    }
    // butterfly reduce across the 4 j-slices
    sx += __shfl_xor(sx, 16, 64);
    sy += __shfl_xor(sy, 16, 64);
    sz += __shfl_xor(sz, 16, 64);
    sw += __shfl_xor(sw, 16, 64);
    sx += __shfl_xor(sx, 32, 64);
    sy += __shfl_xor(sy, 32, 64);
    sz += __shfl_xor(sz, 32, 64);
    sw += __shfl_xor(sw, 32, 64);

    if (j != 0) return;

    double dg = sw + 1e-12;
    double vx = -sx / dg, vy = -sy / dg, vz = -sz / dg;

    double t = (double)t_sqrt[c];     t = (t * t) / (double)N_STEPS;
    double a = (double)alpha_sqrt[c]; a = a * a;
    double b = (double)beta_sqrt[c];  b = b * b;

    double nrm = sqrt(vx * vx + vy * vy + vz * vz + EPS_D);
    double d = 1.0 / (1.0 + exp(-b * (nrm - a)));
    double scale = (nrm * d <= 1.0) ? d : (1.0 / nrm);
    double fs = -scale * t;
    vx *= fs; vy *= fs; vz *= fs;

    double n = sqrt(vx * vx + vy * vy + vz * vz + 1e-16);
    double cn = cos(n);
    double sf = sin(n) / n;

    TO* xo = xout + ((size_t)i * N_CH + c) * DIM;
    xo[0] = (TO)(cn * ax + sf * vx);
    xo[1] = (TO)(cn * ay + sf * vy);
    xo[2] = (TO)(cn * az + sf * vz);
}

// ===========================================================================
// Fallback (round-1 fp32 atomic path, which passed) if d_ws too small
// ===========================================================================
__global__ void deg_kernel(const int* __restrict__ senders,
                           const float* __restrict__ weights,
                           float* __restrict__ deg) {
    int e = blockIdx.x * blockDim.x + threadIdx.x;
    if (e < N_EDGES) atomicAdd(&deg[senders[e]], weights[e]);
}

__global__ void edge_kernel(const float* __restrict__ x,
                            const int* __restrict__ senders,
                            const int* __restrict__ receivers,
                            const float* __restrict__ weights,
                            float* __restrict__ agg) {
    unsigned int tid = blockIdx.x * blockDim.x + threadIdx.x;
    if (tid >= (unsigned int)N_EDGES * N_CH) return;
    unsigned int e = tid >> 4;
    unsigned int c = tid & 15u;
    int s = senders[e];
    int r = receivers[e];
    float w = weights[e];
    const float* xs = x + ((size_t)s * N_CH + c) * DIM;
    const float* xr = x + ((size_t)r * N_CH + c) * DIM;
    float ax = xs[0], ay = xs[1], az = xs[2];
    float bx = xr[0], by = xr[1], bz = xr[2];
    float cd = ax * bx + ay * by + az * bz;
    cd = fminf(fmaxf(cd, -1.0f + 1e-7f), 1.0f - 1e-7f);
    float theta = acosf(cd);
    float sn = sqrtf(fmaxf(1.0f - cd * cd, 0.0f));
    float f = w * theta / sn;
    float* ag = agg + ((size_t)s * N_CH + c) * DIM;
    atomicAdd(&ag[0], f * (bx - cd * ax));
    atomicAdd(&ag[1], f * (by - cd * ay));
    atomicAdd(&ag[2], f * (bz - cd * az));
}

__global__ void node_kernel(const float* __restrict__ xin,
                            const float* __restrict__ agg,
                            const float* __restrict__ deg,
                            const float* __restrict__ t_sqrt,
                            const float* __restrict__ alpha_sqrt,
                            const float* __restrict__ beta_sqrt,
                            float* __restrict__ xout) {
    unsigned int tid = blockIdx.x * blockDim.x + threadIdx.x;
    if (tid >= (unsigned int)N_NODES * N_CH) return;
    unsigned int i = tid >> 4;
    unsigned int c = tid & 15u;
    float dg = deg[i] + 1e-12f;
    const float* ag = agg + (size_t)tid * DIM;
    float vx = -ag[0] / dg, vy = -ag[1] / dg, vz = -ag[2] / dg;
    float t = t_sqrt[c]; t = (t * t) * (1.0f / N_STEPS);
    float a = alpha_sqrt[c]; a = a * a;
    float b = beta_sqrt[c]; b = b * b;
    float nrm = sqrtf(vx * vx + vy * vy + vz * vz + 1.1920929e-7f);
    float d = 1.0f / (1.0f + __expf(-b * (nrm - a)));
    float scale = (nrm * d <= 1.0f) ? d : (1.0f / nrm);
    float fs = -scale * t;
    vx *= fs; vy *= fs; vz *= fs;
    const float* xi = xin + (size_t)tid * DIM;
    float axx = xi[0], ayy = xi[1], azz = xi[2];
    float n = sqrtf(vx * vx + vy * vy + vz * vz + 1e-16f);
    float cn = cosf(n);
    float sf = sinf(n) / n;
    float* xo = xout + (size_t)tid * DIM;
    xo[0] = cn * axx + sf * vx;
    xo[1] = cn * ayy + sf * vy;
    xo[2] = cn * azz + sf * vz;
}

extern "C" void kernel_launch(void* const* d_in, const int* in_sizes, int n_in,
                              void* d_out, int out_size, void* d_ws, size_t ws_size,
                              hipStream_t stream) {
    const float* nodes      = (const float*)d_in[0];
    const int*   senders    = (const int*)d_in[1];
    const int*   receivers  = (const int*)d_in[2];
    const float* weights    = (const float*)d_in[3];
    const float* t_sqrt     = (const float*)d_in[4];
    const float* alpha_sqrt = (const float*)d_in[5];
    const float* beta_sqrt  = (const float*)d_in[6];
    float* out = (float*)d_out;

    // --- workspace layout (fp64 CSR path) ---
    const size_t xtmp_b   = (size_t)N_NODES * N_CH * DIM * sizeof(double); // 38.4 MB
    const size_t rowptr_b = ((size_t)(N_NODES + 1) * sizeof(int) + 255) & ~(size_t)255;
    const size_t cnt_b    = ((size_t)N_NODES * sizeof(int) + 255) & ~(size_t)255;
    const size_t cols_b   = (size_t)N_EDGES * sizeof(int);
    const size_t wv_b     = (size_t)N_EDGES * sizeof(float);
    const size_t need     = xtmp_b + rowptr_b + cnt_b + cols_b + wv_b;    // ~52 MB

    if (ws_size >= need) {
        char* p = (char*)d_ws;
        double* xtmp  = (double*)p;           p += xtmp_b;
        int*   rowptr = (int*)p;              p += rowptr_b;
        int*   cnt    = (int*)p;              p += cnt_b;
        int*   cols   = (int*)p;              p += cols_b;
        float* wv     = (float*)p;

        // CSR build
        hipMemsetAsync(cnt, 0, (size_t)N_NODES * sizeof(int), stream);
        hist_kernel<<<(N_EDGES + 255) / 256, 256, 0, stream>>>(senders, cnt);
        scan_kernel<<<1, SCAN_BLOCK, 0, stream>>>(cnt, rowptr);
        hipMemsetAsync(cnt, 0, (size_t)N_NODES * sizeof(int), stream);
        scatter_kernel<<<(N_EDGES + 255) / 256, 256, 0, stream>>>(
            senders, receivers, weights, rowptr, cnt, cols, wv);

        // two fused flow steps, fp64 carried through
        int grid = (N_NODES + 3) / 4;
        flow_kernel<float, double><<<grid, 256, 0, stream>>>(
            nodes, rowptr, cols, wv, t_sqrt, alpha_sqrt, beta_sqrt, xtmp);
        flow_kernel<double, float><<<grid, 256, 0, stream>>>(
            xtmp, rowptr, cols, wv, t_sqrt, alpha_sqrt, beta_sqrt, out);
    } else {
        // fallback: round-1 fp32 atomic-scatter path (passed at 1.3e-2)
        float* agg = (float*)d_ws;
        float* deg = agg + (size_t)N_NODES * N_CH * DIM;
        hipMemsetAsync(deg, 0, N_NODES * sizeof(float), stream);
        deg_kernel<<<(N_EDGES + 255) / 256, 256, 0, stream>>>(senders, weights, deg);
        const float* xin = nodes;
        for (int step = 0; step < N_STEPS; ++step) {
            hipMemsetAsync(agg, 0, (size_t)N_NODES * N_CH * DIM * sizeof(float), stream);
            unsigned int n_ec = (unsigned int)N_EDGES * N_CH;
            edge_kernel<<<(n_ec + 255) / 256, 256, 0, stream>>>(xin, senders, receivers,
                                                                weights, agg);
            unsigned int n_nc = (unsigned int)N_NODES * N_CH;
            node_kernel<<<(n_nc + 255) / 256, 256, 0, stream>>>(xin, agg, deg, t_sqrt,
                                                                alpha_sqrt, beta_sqrt, out);
            xin = out;
        }
    }
}

// Round 5
// 553.002 us; speedup vs baseline: 2.8787x; 1.3126x over previous
//
#include <hip/hip_runtime.h>

#define N_NODES 100000
#define N_CH 16
#define DIM 3
#define N_EDGES 1600000
#define N_STEPS 2
// float32 machine eps (reference wraps jnp.finfo(float32).eps)
#define EPS_D 1.1920928955078125e-7

#define PB 1024
#define NBLK ((N_NODES + PB - 1) / PB)   // 98

// ===========================================================================
// CSR build: histogram -> parallel exclusive scan -> scatter edge payloads
// ===========================================================================
__global__ void hist_kernel(const int* __restrict__ senders,
                            int* __restrict__ cnt) {
    int e = blockIdx.x * blockDim.x + threadIdx.x;
    if (e < N_EDGES) atomicAdd(&cnt[senders[e]], 1);
}

// per-block sums of cnt
__global__ void scan_partials(const int* __restrict__ cnt,
                              int* __restrict__ part) {
    __shared__ int sh[PB];
    int t = threadIdx.x;
    int g = blockIdx.x * PB + t;
    int v = (g < N_NODES) ? cnt[g] : 0;
    sh[t] = v;
    __syncthreads();
    for (int off = PB / 2; off > 0; off >>= 1) {
        if (t < off) sh[t] += sh[t + off];
        __syncthreads();
    }
    if (t == 0) part[blockIdx.x] = sh[0];
}

// single small block: exclusive-scan the NBLK partials; write total
__global__ void scan_mid(int* __restrict__ part, int* __restrict__ rowptr) {
    __shared__ int sh[128];
    int t = threadIdx.x;
    int v = (t < NBLK) ? part[t] : 0;
    sh[t] = v;
    __syncthreads();
    for (int off = 1; off < 128; off <<= 1) {
        int u = (t >= off) ? sh[t - off] : 0;
        __syncthreads();
        sh[t] += u;
        __syncthreads();
    }
    if (t < NBLK) part[t] = sh[t] - v;          // exclusive block offset
    if (t == NBLK - 1) rowptr[N_NODES] = sh[t]; // total (= N_EDGES)
}

// block-wide exclusive scan + block offset -> rowptr
__global__ void scan_apply(const int* __restrict__ cnt,
                           const int* __restrict__ part,
                           int* __restrict__ rowptr) {
    __shared__ int sh[PB];
    int t = threadIdx.x;
    int g = blockIdx.x * PB + t;
    int v = (g < N_NODES) ? cnt[g] : 0;
    sh[t] = v;
    __syncthreads();
    for (int off = 1; off < PB; off <<= 1) {
        int u = (t >= off) ? sh[t - off] : 0;
        __syncthreads();
        sh[t] += u;
        __syncthreads();
    }
    if (g < N_NODES) rowptr[g] = part[blockIdx.x] + sh[t] - v;
}

__global__ void scatter_kernel(const int* __restrict__ senders,
                               const int* __restrict__ receivers,
                               const float* __restrict__ weights,
                               const int* __restrict__ rowptr,
                               int* __restrict__ fill,
                               int* __restrict__ cols,
                               float* __restrict__ wv) {
    int e = blockIdx.x * blockDim.x + threadIdx.x;
    if (e >= N_EDGES) return;
    int s = senders[e];
    int pos = rowptr[s] + atomicAdd(&fill[s], 1);
    cols[pos] = receivers[e];
    wv[pos] = weights[e];
}

// ===========================================================================
// f0(cd) = acos(cd)/sqrt(1-cd^2), fused, fp64, rel err < ~1e-11.
// A(z) = asin(sqrt(z))/sqrt(z), Taylor deg 14, z in [0, 0.25].
// ===========================================================================
__device__ __forceinline__ double theta_over_sin(double cd) {
    double acd = fabs(cd);
    bool mid = (acd <= 0.5);
    double z = mid ? (cd * cd) : (0.5 * (1.0 - acd));   // z <= 0.25 both ways
    double A = 0.0051533097;
    A = fma(A, z, 0.0057400377);
    A = fma(A, z, 0.0064472098);
    A = fma(A, z, 0.0073125260);
    A = fma(A, z, 0.0083903358);
    A = fma(A, z, 0.0097616095);
    A = fma(A, z, 0.0115518009);
    A = fma(A, z, 0.0139648437500);
    A = fma(A, z, 0.0173527644231);
    A = fma(A, z, 0.0223721590909);
    A = fma(A, z, 0.0303819444444);
    A = fma(A, z, 0.0446428571429);
    A = fma(A, z, 0.075);
    A = fma(A, z, 0.16666666666666666);
    A = fma(A, z, 1.0);
    double r1 = rsqrt(mid ? (1.0 - z) : (4.0 - 4.0 * z));
    double rq = rsqrt(z);   // used only when cd < -0.5 (z >= 5e-8 there)
    double u;
    if (mid) {
        u = 1.5707963267948966 - cd * A;                 // acos(cd)
    } else if (cd > 0.0) {
        u = 2.0 * A;                                     // theta/sn folded
    } else {
        u = fma(3.141592653589793, rq, -2.0 * A);
    }
    return u * r1;
}

// ===========================================================================
// Fused flow step, full fp64. One wave64 per node, lane = c + 16*j.
// ===========================================================================
template <typename TI, typename TO>
__global__ void flow_kernel(const TI* __restrict__ x,
                            const int* __restrict__ rowptr,
                            const int* __restrict__ cols,
                            const float* __restrict__ wv,
                            const float* __restrict__ t_sqrt,
                            const float* __restrict__ alpha_sqrt,
                            const float* __restrict__ beta_sqrt,
                            TO* __restrict__ xout) {
    int wave = threadIdx.x >> 6;                 // 4 waves / block
    int lane = threadIdx.x & 63;
    int i = blockIdx.x * 4 + wave;
    if (i >= N_NODES) return;
    int c = lane & 15;
    int j = lane >> 4;

    int beg = rowptr[i];
    int end = rowptr[i + 1];

    const TI* xi = x + ((size_t)i * N_CH + c) * DIM;
    double ax = (double)xi[0], ay = (double)xi[1], az = (double)xi[2];

    double sx = 0.0, sy = 0.0, sz = 0.0, sw = 0.0;
    #pragma unroll 2
    for (int k = beg + j; k < end; k += 4) {
        int r = cols[k];
        double w = (double)wv[k];
        const TI* xr = x + ((size_t)r * N_CH + c) * DIM;
        double bx = (double)xr[0], by = (double)xr[1], bz = (double)xr[2];

        double cd = ax * bx + ay * by + az * bz;
        cd = fmin(fmax(cd, -1.0 + 1e-7), 1.0 - 1e-7);
        double f = w * theta_over_sin(cd);

        sx += f * (bx - cd * ax);
        sy += f * (by - cd * ay);
        sz += f * (bz - cd * az);
        sw += w;
    }
    // butterfly reduce across the 4 j-slices
    sx += __shfl_xor(sx, 16, 64);
    sy += __shfl_xor(sy, 16, 64);
    sz += __shfl_xor(sz, 16, 64);
    sw += __shfl_xor(sw, 16, 64);
    sx += __shfl_xor(sx, 32, 64);
    sy += __shfl_xor(sy, 32, 64);
    sz += __shfl_xor(sz, 32, 64);
    sw += __shfl_xor(sw, 32, 64);

    if (j != 0) return;

    double dg = sw + 1e-12;
    double vx = -sx / dg, vy = -sy / dg, vz = -sz / dg;

    double t = (double)t_sqrt[c];     t = (t * t) / (double)N_STEPS;
    double a = (double)alpha_sqrt[c]; a = a * a;
    double b = (double)beta_sqrt[c];  b = b * b;

    double nrm = sqrt(vx * vx + vy * vy + vz * vz + EPS_D);
    double d = 1.0 / (1.0 + exp(-b * (nrm - a)));
    double scale = (nrm * d <= 1.0) ? d : (1.0 / nrm);
    double fs = -scale * t;
    vx *= fs; vy *= fs; vz *= fs;

    double n = sqrt(vx * vx + vy * vy + vz * vz + 1e-16);
    double cn = cos(n);
    double sf = sin(n) / n;

    TO* xo = xout + ((size_t)i * N_CH + c) * DIM;
    xo[0] = (TO)(cn * ax + sf * vx);
    xo[1] = (TO)(cn * ay + sf * vy);
    xo[2] = (TO)(cn * az + sf * vz);
}

// ===========================================================================
// Fallback (round-1 fp32 atomic path, which passed) if d_ws too small
// ===========================================================================
__global__ void deg_kernel(const int* __restrict__ senders,
                           const float* __restrict__ weights,
                           float* __restrict__ deg) {
    int e = blockIdx.x * blockDim.x + threadIdx.x;
    if (e < N_EDGES) atomicAdd(&deg[senders[e]], weights[e]);
}

__global__ void edge_kernel(const float* __restrict__ x,
                            const int* __restrict__ senders,
                            const int* __restrict__ receivers,
                            const float* __restrict__ weights,
                            float* __restrict__ agg) {
    unsigned int tid = blockIdx.x * blockDim.x + threadIdx.x;
    if (tid >= (unsigned int)N_EDGES * N_CH) return;
    unsigned int e = tid >> 4;
    unsigned int c = tid & 15u;
    int s = senders[e];
    int r = receivers[e];
    float w = weights[e];
    const float* xs = x + ((size_t)s * N_CH + c) * DIM;
    const float* xr = x + ((size_t)r * N_CH + c) * DIM;
    float ax = xs[0], ay = xs[1], az = xs[2];
    float bx = xr[0], by = xr[1], bz = xr[2];
    float cd = ax * bx + ay * by + az * bz;
    cd = fminf(fmaxf(cd, -1.0f + 1e-7f), 1.0f - 1e-7f);
    float theta = acosf(cd);
    float sn = sqrtf(fmaxf(1.0f - cd * cd, 0.0f));
    float f = w * theta / sn;
    float* ag = agg + ((size_t)s * N_CH + c) * DIM;
    atomicAdd(&ag[0], f * (bx - cd * ax));
    atomicAdd(&ag[1], f * (by - cd * ay));
    atomicAdd(&ag[2], f * (bz - cd * az));
}

__global__ void node_kernel(const float* __restrict__ xin,
                            const float* __restrict__ agg,
                            const float* __restrict__ deg,
                            const float* __restrict__ t_sqrt,
                            const float* __restrict__ alpha_sqrt,
                            const float* __restrict__ beta_sqrt,
                            float* __restrict__ xout) {
    unsigned int tid = blockIdx.x * blockDim.x + threadIdx.x;
    if (tid >= (unsigned int)N_NODES * N_CH) return;
    unsigned int i = tid >> 4;
    unsigned int c = tid & 15u;
    float dg = deg[i] + 1e-12f;
    const float* ag = agg + (size_t)tid * DIM;
    float vx = -ag[0] / dg, vy = -ag[1] / dg, vz = -ag[2] / dg;
    float t = t_sqrt[c]; t = (t * t) * (1.0f / N_STEPS);
    float a = alpha_sqrt[c]; a = a * a;
    float b = beta_sqrt[c]; b = b * b;
    float nrm = sqrtf(vx * vx + vy * vy + vz * vz + 1.1920929e-7f);
    float d = 1.0f / (1.0f + __expf(-b * (nrm - a)));
    float scale = (nrm * d <= 1.0f) ? d : (1.0f / nrm);
    float fs = -scale * t;
    vx *= fs; vy *= fs; vz *= fs;
    const float* xi = xin + (size_t)tid * DIM;
    float axx = xi[0], ayy = xi[1], azz = xi[2];
    float n = sqrtf(vx * vx + vy * vy + vz * vz + 1e-16f);
    float cn = cosf(n);
    float sf = sinf(n) / n;
    float* xo = xout + (size_t)tid * DIM;
    xo[0] = cn * axx + sf * vx;
    xo[1] = cn * ayy + sf * vy;
    xo[2] = cn * azz + sf * vz;
}

extern "C" void kernel_launch(void* const* d_in, const int* in_sizes, int n_in,
                              void* d_out, int out_size, void* d_ws, size_t ws_size,
                              hipStream_t stream) {
    const float* nodes      = (const float*)d_in[0];
    const int*   senders    = (const int*)d_in[1];
    const int*   receivers  = (const int*)d_in[2];
    const float* weights    = (const float*)d_in[3];
    const float* t_sqrt     = (const float*)d_in[4];
    const float* alpha_sqrt = (const float*)d_in[5];
    const float* beta_sqrt  = (const float*)d_in[6];
    float* out = (float*)d_out;

    // --- workspace layout (fp64 CSR path) ---
    const size_t xtmp_b   = (size_t)N_NODES * N_CH * DIM * sizeof(double); // 38.4 MB
    const size_t rowptr_b = ((size_t)(N_NODES + 1) * sizeof(int) + 255) & ~(size_t)255;
    const size_t cnt_b    = ((size_t)N_NODES * sizeof(int) + 255) & ~(size_t)255;
    const size_t part_b   = 4096;
    const size_t cols_b   = (size_t)N_EDGES * sizeof(int);
    const size_t wv_b     = (size_t)N_EDGES * sizeof(float);
    const size_t need     = xtmp_b + rowptr_b + cnt_b + part_b + cols_b + wv_b;

    if (ws_size >= need) {
        char* p = (char*)d_ws;
        double* xtmp  = (double*)p;           p += xtmp_b;
        int*   rowptr = (int*)p;              p += rowptr_b;
        int*   cnt    = (int*)p;              p += cnt_b;
        int*   part   = (int*)p;              p += part_b;
        int*   cols   = (int*)p;              p += cols_b;
        float* wv     = (float*)p;

        // CSR build
        hipMemsetAsync(cnt, 0, (size_t)N_NODES * sizeof(int), stream);
        hist_kernel<<<(N_EDGES + 255) / 256, 256, 0, stream>>>(senders, cnt);
        scan_partials<<<NBLK, PB, 0, stream>>>(cnt, part);
        scan_mid<<<1, 128, 0, stream>>>(part, rowptr);
        scan_apply<<<NBLK, PB, 0, stream>>>(cnt, part, rowptr);
        hipMemsetAsync(cnt, 0, (size_t)N_NODES * sizeof(int), stream);
        scatter_kernel<<<(N_EDGES + 255) / 256, 256, 0, stream>>>(
            senders, receivers, weights, rowptr, cnt, cols, wv);

        // two fused flow steps, fp64 carried through
        int grid = (N_NODES + 3) / 4;
        flow_kernel<float, double><<<grid, 256, 0, stream>>>(
            nodes, rowptr, cols, wv, t_sqrt, alpha_sqrt, beta_sqrt, xtmp);
        flow_kernel<double, float><<<grid, 256, 0, stream>>>(
            xtmp, rowptr, cols, wv, t_sqrt, alpha_sqrt, beta_sqrt, out);
    } else {
        // fallback: round-1 fp32 atomic-scatter path (passed at 1.3e-2)
        float* agg = (float*)d_ws;
        float* deg = agg + (size_t)N_NODES * N_CH * DIM;
        hipMemsetAsync(deg, 0, N_NODES * sizeof(float), stream);
        deg_kernel<<<(N_EDGES + 255) / 256, 256, 0, stream>>>(senders, weights, deg);
        const float* xin = nodes;
        for (int step = 0; step < N_STEPS; ++step) {
            hipMemsetAsync(agg, 0, (size_t)N_NODES * N_CH * DIM * sizeof(float), stream);
            unsigned int n_ec = (unsigned int)N_EDGES * N_CH;
            edge_kernel<<<(n_ec + 255) / 256, 256, 0, stream>>>(xin, senders, receivers,
                                                                weights, agg);
            unsigned int n_nc = (unsigned int)N_NODES * N_CH;
            node_kernel<<<(n_nc + 255) / 256, 256, 0, stream>>>(xin, agg, deg, t_sqrt,
                                                                alpha_sqrt, beta_sqrt, out);
            xin = out;
        }
    }
}

// Round 6
// 406.760 us; speedup vs baseline: 3.9137x; 1.3595x over previous
//
#include <hip/hip_runtime.h>

#define N_NODES 100000
#define N_CH 16
#define DIM 3
#define N_EDGES 1600000
#define N_STEPS 2
// float32 machine eps (reference wraps jnp.finfo(float32).eps)
#define EPS_D 1.1920928955078125e-7

#define PB 1024
#define NBLK ((N_NODES + PB - 1) / PB)   // 98

// ===========================================================================
// CSR build: histogram -> parallel exclusive scan -> scatter edge payloads
// ===========================================================================
__global__ void hist_kernel(const int* __restrict__ senders,
                            int* __restrict__ cnt) {
    int e = blockIdx.x * blockDim.x + threadIdx.x;
    if (e < N_EDGES) atomicAdd(&cnt[senders[e]], 1);
}

__global__ void scan_partials(const int* __restrict__ cnt,
                              int* __restrict__ part) {
    __shared__ int sh[PB];
    int t = threadIdx.x;
    int g = blockIdx.x * PB + t;
    int v = (g < N_NODES) ? cnt[g] : 0;
    sh[t] = v;
    __syncthreads();
    for (int off = PB / 2; off > 0; off >>= 1) {
        if (t < off) sh[t] += sh[t + off];
        __syncthreads();
    }
    if (t == 0) part[blockIdx.x] = sh[0];
}

__global__ void scan_mid(int* __restrict__ part, int* __restrict__ rowptr) {
    __shared__ int sh[128];
    int t = threadIdx.x;
    int v = (t < NBLK) ? part[t] : 0;
    sh[t] = v;
    __syncthreads();
    for (int off = 1; off < 128; off <<= 1) {
        int u = (t >= off) ? sh[t - off] : 0;
        __syncthreads();
        sh[t] += u;
        __syncthreads();
    }
    if (t < NBLK) part[t] = sh[t] - v;
    if (t == NBLK - 1) rowptr[N_NODES] = sh[t];
}

__global__ void scan_apply(const int* __restrict__ cnt,
                           const int* __restrict__ part,
                           int* __restrict__ rowptr) {
    __shared__ int sh[PB];
    int t = threadIdx.x;
    int g = blockIdx.x * PB + t;
    int v = (g < N_NODES) ? cnt[g] : 0;
    sh[t] = v;
    __syncthreads();
    for (int off = 1; off < PB; off <<= 1) {
        int u = (t >= off) ? sh[t - off] : 0;
        __syncthreads();
        sh[t] += u;
        __syncthreads();
    }
    if (g < N_NODES) rowptr[g] = part[blockIdx.x] + sh[t] - v;
}

// pack (receiver, weight-bits) into int2 so the flow loop does one 8B load
__global__ void scatter_kernel(const int* __restrict__ senders,
                               const int* __restrict__ receivers,
                               const float* __restrict__ weights,
                               const int* __restrict__ rowptr,
                               int* __restrict__ fill,
                               int2* __restrict__ edata) {
    int e = blockIdx.x * blockDim.x + threadIdx.x;
    if (e >= N_EDGES) return;
    int s = senders[e];
    int pos = rowptr[s] + atomicAdd(&fill[s], 1);
    edata[pos] = make_int2(receivers[e], __float_as_int(weights[e]));
}

// ===========================================================================
// f0(cd) = acos(cd)/sqrt(1-cd^2), fused, fp64, rel err < ~1e-11.
// (unchanged from round 5 — numerics frozen)
// ===========================================================================
__device__ __forceinline__ double theta_over_sin(double cd) {
    double acd = fabs(cd);
    bool mid = (acd <= 0.5);
    double z = mid ? (cd * cd) : (0.5 * (1.0 - acd));
    double A = 0.0051533097;
    A = fma(A, z, 0.0057400377);
    A = fma(A, z, 0.0064472098);
    A = fma(A, z, 0.0073125260);
    A = fma(A, z, 0.0083903358);
    A = fma(A, z, 0.0097616095);
    A = fma(A, z, 0.0115518009);
    A = fma(A, z, 0.0139648437500);
    A = fma(A, z, 0.0173527644231);
    A = fma(A, z, 0.0223721590909);
    A = fma(A, z, 0.0303819444444);
    A = fma(A, z, 0.0446428571429);
    A = fma(A, z, 0.075);
    A = fma(A, z, 0.16666666666666666);
    A = fma(A, z, 1.0);
    double r1 = rsqrt(mid ? (1.0 - z) : (4.0 - 4.0 * z));
    double rq = rsqrt(z);
    double u;
    if (mid) {
        u = 1.5707963267948966 - cd * A;
    } else if (cd > 0.0) {
        u = 2.0 * A;
    } else {
        u = fma(3.141592653589793, rq, -2.0 * A);
    }
    return u * r1;
}

// ===========================================================================
// Fused flow step v2: 4 nodes per wave, lane = c + 16*q.
// Each lane owns one (node, channel): serial accumulate over the node's CSR
// row (no shuffles), then full-lane fp64 epilogue (amortized over 4 nodes).
// N_NODES = 6250 * 16 exactly -> no tail.
// ===========================================================================
template <typename TI, typename TO>
__global__ void flow_kernel(const TI* __restrict__ x,
                            const int* __restrict__ rowptr,
                            const int2* __restrict__ edata,
                            const float* __restrict__ t_sqrt,
                            const float* __restrict__ alpha_sqrt,
                            const float* __restrict__ beta_sqrt,
                            TO* __restrict__ xout) {
    int wave = threadIdx.x >> 6;                  // 4 waves / block
    int lane = threadIdx.x & 63;
    int q = lane >> 4;                            // node slot in wave
    int c = lane & 15;                            // channel
    int i = (blockIdx.x * 4 + wave) * 4 + q;      // 16 nodes / block

    int beg = rowptr[i];
    int end = rowptr[i + 1];

    const TI* xi = x + ((size_t)i * N_CH + c) * DIM;
    double ax = (double)xi[0], ay = (double)xi[1], az = (double)xi[2];

    double sx = 0.0, sy = 0.0, sz = 0.0, sw = 0.0;
    for (int k = beg; k < end; ++k) {
        int2 ed = edata[k];
        int r = ed.x;
        double w = (double)__int_as_float(ed.y);
        const TI* xr = x + ((size_t)r * N_CH + c) * DIM;
        double bx = (double)xr[0], by = (double)xr[1], bz = (double)xr[2];

        double cd = ax * bx + ay * by + az * bz;
        cd = fmin(fmax(cd, -1.0 + 1e-7), 1.0 - 1e-7);
        double f = w * theta_over_sin(cd);

        sx += f * (bx - cd * ax);
        sy += f * (by - cd * ay);
        sz += f * (bz - cd * az);
        sw += w;
    }

    double dg = sw + 1e-12;
    double vx = -sx / dg, vy = -sy / dg, vz = -sz / dg;

    double t = (double)t_sqrt[c];     t = (t * t) / (double)N_STEPS;
    double a = (double)alpha_sqrt[c]; a = a * a;
    double b = (double)beta_sqrt[c];  b = b * b;

    double nrm = sqrt(vx * vx + vy * vy + vz * vz + EPS_D);
    double d = 1.0 / (1.0 + exp(-b * (nrm - a)));
    double scale = (nrm * d <= 1.0) ? d : (1.0 / nrm);
    double fs = -scale * t;
    vx *= fs; vy *= fs; vz *= fs;

    double n = sqrt(vx * vx + vy * vy + vz * vz + 1e-16);
    double cn = cos(n);
    double sf = sin(n) / n;

    TO* xo = xout + ((size_t)i * N_CH + c) * DIM;
    xo[0] = (TO)(cn * ax + sf * vx);
    xo[1] = (TO)(cn * ay + sf * vy);
    xo[2] = (TO)(cn * az + sf * vz);
}

// ===========================================================================
// Fallback (round-1 fp32 atomic path, which passed) if d_ws too small
// ===========================================================================
__global__ void deg_kernel(const int* __restrict__ senders,
                           const float* __restrict__ weights,
                           float* __restrict__ deg) {
    int e = blockIdx.x * blockDim.x + threadIdx.x;
    if (e < N_EDGES) atomicAdd(&deg[senders[e]], weights[e]);
}

__global__ void edge_kernel(const float* __restrict__ x,
                            const int* __restrict__ senders,
                            const int* __restrict__ receivers,
                            const float* __restrict__ weights,
                            float* __restrict__ agg) {
    unsigned int tid = blockIdx.x * blockDim.x + threadIdx.x;
    if (tid >= (unsigned int)N_EDGES * N_CH) return;
    unsigned int e = tid >> 4;
    unsigned int c = tid & 15u;
    int s = senders[e];
    int r = receivers[e];
    float w = weights[e];
    const float* xs = x + ((size_t)s * N_CH + c) * DIM;
    const float* xr = x + ((size_t)r * N_CH + c) * DIM;
    float ax = xs[0], ay = xs[1], az = xs[2];
    float bx = xr[0], by = xr[1], bz = xr[2];
    float cd = ax * bx + ay * by + az * bz;
    cd = fminf(fmaxf(cd, -1.0f + 1e-7f), 1.0f - 1e-7f);
    float theta = acosf(cd);
    float sn = sqrtf(fmaxf(1.0f - cd * cd, 0.0f));
    float f = w * theta / sn;
    float* ag = agg + ((size_t)s * N_CH + c) * DIM;
    atomicAdd(&ag[0], f * (bx - cd * ax));
    atomicAdd(&ag[1], f * (by - cd * ay));
    atomicAdd(&ag[2], f * (bz - cd * az));
}

__global__ void node_kernel(const float* __restrict__ xin,
                            const float* __restrict__ agg,
                            const float* __restrict__ deg,
                            const float* __restrict__ t_sqrt,
                            const float* __restrict__ alpha_sqrt,
                            const float* __restrict__ beta_sqrt,
                            float* __restrict__ xout) {
    unsigned int tid = blockIdx.x * blockDim.x + threadIdx.x;
    if (tid >= (unsigned int)N_NODES * N_CH) return;
    unsigned int i = tid >> 4;
    unsigned int c = tid & 15u;
    float dg = deg[i] + 1e-12f;
    const float* ag = agg + (size_t)tid * DIM;
    float vx = -ag[0] / dg, vy = -ag[1] / dg, vz = -ag[2] / dg;
    float t = t_sqrt[c]; t = (t * t) * (1.0f / N_STEPS);
    float a = alpha_sqrt[c]; a = a * a;
    float b = beta_sqrt[c]; b = b * b;
    float nrm = sqrtf(vx * vx + vy * vy + vz * vz + 1.1920929e-7f);
    float d = 1.0f / (1.0f + __expf(-b * (nrm - a)));
    float scale = (nrm * d <= 1.0f) ? d : (1.0f / nrm);
    float fs = -scale * t;
    vx *= fs; vy *= fs; vz *= fs;
    const float* xi = xin + (size_t)tid * DIM;
    float axx = xi[0], ayy = xi[1], azz = xi[2];
    float n = sqrtf(vx * vx + vy * vy + vz * vz + 1e-16f);
    float cn = cosf(n);
    float sf = sinf(n) / n;
    float* xo = xout + (size_t)tid * DIM;
    xo[0] = cn * axx + sf * vx;
    xo[1] = cn * ayy + sf * vy;
    xo[2] = cn * azz + sf * vz;
}

extern "C" void kernel_launch(void* const* d_in, const int* in_sizes, int n_in,
                              void* d_out, int out_size, void* d_ws, size_t ws_size,
                              hipStream_t stream) {
    const float* nodes      = (const float*)d_in[0];
    const int*   senders    = (const int*)d_in[1];
    const int*   receivers  = (const int*)d_in[2];
    const float* weights    = (const float*)d_in[3];
    const float* t_sqrt     = (const float*)d_in[4];
    const float* alpha_sqrt = (const float*)d_in[5];
    const float* beta_sqrt  = (const float*)d_in[6];
    float* out = (float*)d_out;

    // --- workspace layout (fp64 CSR path) — same total as proven round-5 ---
    const size_t xtmp_b   = (size_t)N_NODES * N_CH * DIM * sizeof(double); // 38.4 MB
    const size_t rowptr_b = ((size_t)(N_NODES + 1) * sizeof(int) + 255) & ~(size_t)255;
    const size_t cnt_b    = ((size_t)N_NODES * sizeof(int) + 255) & ~(size_t)255;
    const size_t part_b   = 4096;
    const size_t edata_b  = (size_t)N_EDGES * sizeof(int2);                // 12.8 MB
    const size_t need     = xtmp_b + rowptr_b + cnt_b + part_b + edata_b;

    if (ws_size >= need) {
        char* p = (char*)d_ws;
        double* xtmp  = (double*)p;           p += xtmp_b;
        int*   rowptr = (int*)p;              p += rowptr_b;
        int*   cnt    = (int*)p;              p += cnt_b;
        int*   part   = (int*)p;              p += part_b;
        int2*  edata  = (int2*)p;

        // CSR build
        hipMemsetAsync(cnt, 0, (size_t)N_NODES * sizeof(int), stream);
        hist_kernel<<<(N_EDGES + 255) / 256, 256, 0, stream>>>(senders, cnt);
        scan_partials<<<NBLK, PB, 0, stream>>>(cnt, part);
        scan_mid<<<1, 128, 0, stream>>>(part, rowptr);
        scan_apply<<<NBLK, PB, 0, stream>>>(cnt, part, rowptr);
        hipMemsetAsync(cnt, 0, (size_t)N_NODES * sizeof(int), stream);
        scatter_kernel<<<(N_EDGES + 255) / 256, 256, 0, stream>>>(
            senders, receivers, weights, rowptr, cnt, edata);

        // two fused flow steps, fp64 carried through; 16 nodes per block
        int grid = N_NODES / 16;   // 6250, exact
        flow_kernel<float, double><<<grid, 256, 0, stream>>>(
            nodes, rowptr, edata, t_sqrt, alpha_sqrt, beta_sqrt, xtmp);
        flow_kernel<double, float><<<grid, 256, 0, stream>>>(
            xtmp, rowptr, edata, t_sqrt, alpha_sqrt, beta_sqrt, out);
    } else {
        // fallback: round-1 fp32 atomic-scatter path (passed at 1.3e-2)
        float* agg = (float*)d_ws;
        float* deg = agg + (size_t)N_NODES * N_CH * DIM;
        hipMemsetAsync(deg, 0, N_NODES * sizeof(float), stream);
        deg_kernel<<<(N_EDGES + 255) / 256, 256, 0, stream>>>(senders, weights, deg);
        const float* xin = nodes;
        for (int step = 0; step < N_STEPS; ++step) {
            hipMemsetAsync(agg, 0, (size_t)N_NODES * N_CH * DIM * sizeof(float), stream);
            unsigned int n_ec = (unsigned int)N_EDGES * N_CH;
            edge_kernel<<<(n_ec + 255) / 256, 256, 0, stream>>>(xin, senders, receivers,
                                                                weights, agg);
            unsigned int n_nc = (unsigned int)N_NODES * N_CH;
            node_kernel<<<(n_nc + 255) / 256, 256, 0, stream>>>(xin, agg, deg, t_sqrt,
                                                                alpha_sqrt, beta_sqrt, out);
            xin = out;
        }
    }
}

// Round 7
// 375.474 us; speedup vs baseline: 4.2398x; 1.0833x over previous
//
#include <hip/hip_runtime.h>

#define N_NODES 100000
#define N_CH 16
#define DIM 3
#define N_EDGES 1600000
#define N_STEPS 2
// float32 machine eps (reference wraps jnp.finfo(float32).eps)
#define EPS_D 1.1920928955078125e-7

#define PB 1024
#define NBLK ((N_NODES + PB - 1) / PB)   // 98
#define DBINS 64

// ===========================================================================
// CSR build: histogram -> parallel exclusive scan -> scatter edge payloads
// ===========================================================================
__global__ void hist_kernel(const int4* __restrict__ senders4,
                            int* __restrict__ cnt) {
    int e = blockIdx.x * blockDim.x + threadIdx.x;
    if (e < N_EDGES / 4) {
        int4 s = senders4[e];
        atomicAdd(&cnt[s.x], 1);
        atomicAdd(&cnt[s.y], 1);
        atomicAdd(&cnt[s.z], 1);
        atomicAdd(&cnt[s.w], 1);
    }
}

__global__ void scan_partials(const int* __restrict__ cnt,
                              int* __restrict__ part) {
    __shared__ int sh[PB];
    int t = threadIdx.x;
    int g = blockIdx.x * PB + t;
    int v = (g < N_NODES) ? cnt[g] : 0;
    sh[t] = v;
    __syncthreads();
    for (int off = PB / 2; off > 0; off >>= 1) {
        if (t < off) sh[t] += sh[t + off];
        __syncthreads();
    }
    if (t == 0) part[blockIdx.x] = sh[0];
}

__global__ void scan_mid(int* __restrict__ part, int* __restrict__ rowptr) {
    __shared__ int sh[128];
    int t = threadIdx.x;
    int v = (t < NBLK) ? part[t] : 0;
    sh[t] = v;
    __syncthreads();
    for (int off = 1; off < 128; off <<= 1) {
        int u = (t >= off) ? sh[t - off] : 0;
        __syncthreads();
        sh[t] += u;
        __syncthreads();
    }
    if (t < NBLK) part[t] = sh[t] - v;
    if (t == NBLK - 1) rowptr[N_NODES] = sh[t];
}

__global__ void scan_apply(const int* __restrict__ cnt,
                           const int* __restrict__ part,
                           int* __restrict__ rowptr) {
    __shared__ int sh[PB];
    int t = threadIdx.x;
    int g = blockIdx.x * PB + t;
    int v = (g < N_NODES) ? cnt[g] : 0;
    sh[t] = v;
    __syncthreads();
    for (int off = 1; off < PB; off <<= 1) {
        int u = (t >= off) ? sh[t - off] : 0;
        __syncthreads();
        sh[t] += u;
        __syncthreads();
    }
    if (g < N_NODES) rowptr[g] = part[blockIdx.x] + sh[t] - v;
}

// ---------------------------------------------------------------------------
// degree-sort (counting sort over DBINS degree bins) -> perm
// ---------------------------------------------------------------------------
__global__ void dsort_hist(const int* __restrict__ cnt,
                           int* __restrict__ bins) {
    __shared__ int lb[DBINS];
    int t = threadIdx.x;
    if (t < DBINS) lb[t] = 0;
    __syncthreads();
    int g = blockIdx.x * blockDim.x + t;
    if (g < N_NODES) {
        int d = cnt[g]; if (d > DBINS - 1) d = DBINS - 1;
        atomicAdd(&lb[d], 1);
    }
    __syncthreads();
    if (t < DBINS && lb[t]) atomicAdd(&bins[t], lb[t]);
}

__global__ void dsort_scan(const int* __restrict__ bins,
                           int* __restrict__ binoff,
                           int* __restrict__ binfill) {
    int t = threadIdx.x;          // one wave of 64
    int v = bins[t];
    int s = v;
    for (int off = 1; off < DBINS; off <<= 1) {
        int u = __shfl_up(s, off, 64);
        if (t >= off) s += u;
    }
    binoff[t] = s - v;
    binfill[t] = 0;
}

__global__ void dsort_scatter(const int* __restrict__ cnt,
                              const int* __restrict__ binoff,
                              int* __restrict__ binfill,
                              int* __restrict__ perm) {
    __shared__ int lcnt[DBINS];
    __shared__ int lbase[DBINS];
    int t = threadIdx.x;
    if (t < DBINS) lcnt[t] = 0;
    __syncthreads();
    int g = blockIdx.x * blockDim.x + t;
    int d = 0, myoff = 0;
    if (g < N_NODES) {
        d = cnt[g]; if (d > DBINS - 1) d = DBINS - 1;
        myoff = atomicAdd(&lcnt[d], 1);
    }
    __syncthreads();
    if (t < DBINS && lcnt[t]) lbase[t] = atomicAdd(&binfill[t], lcnt[t]);
    __syncthreads();
    if (g < N_NODES) perm[binoff[d] + lbase[d] + myoff] = g;
}

// edge scatter: consumes cnt by atomic decrement (no fill memset needed)
__global__ void scatter_kernel(const int* __restrict__ senders,
                               const int* __restrict__ receivers,
                               const float* __restrict__ weights,
                               const int* __restrict__ rowptr,
                               int* __restrict__ cnt,
                               int2* __restrict__ edata) {
    int e = blockIdx.x * blockDim.x + threadIdx.x;
    if (e >= N_EDGES) return;
    int s = senders[e];
    int old = atomicAdd(&cnt[s], -1);
    edata[rowptr[s] + old - 1] = make_int2(receivers[e], __float_as_int(weights[e]));
}

// ===========================================================================
// fast fp64 rsqrt: fp32 seed + one fp64 Newton (rel err ~3e-14; args are
// normal-range positives here)
// ===========================================================================
__device__ __forceinline__ double fast_rsqrt(double x) {
    double y = (double)rsqrtf((float)x);
    y = y * fma(-0.5 * x, y * y, 1.5);
    return y;
}

// f0(cd) = acos(cd)/sqrt(1-cd^2), fp64, rel err < ~2e-9 (benign region) and
// ~1e-13 near |cd|=1 (the amplification-critical region, z->0).
__device__ __forceinline__ double theta_over_sin(double cd) {
    double acd = fabs(cd);
    bool mid = (acd <= 0.5);
    double z = mid ? (cd * cd) : (0.5 * (1.0 - acd));   // z in [0, 0.25]
    double A = 0.008390335809943149;                    // asin(sqrt(z))/sqrt(z)
    A = fma(A, z, 0.009761609529194078);
    A = fma(A, z, 0.011551800896139706);
    A = fma(A, z, 0.013964843750);
    A = fma(A, z, 0.017352764423076924);
    A = fma(A, z, 0.022372159090909092);
    A = fma(A, z, 0.030381944444444444);
    A = fma(A, z, 0.044642857142857144);
    A = fma(A, z, 0.075);
    A = fma(A, z, 0.16666666666666666);
    A = fma(A, z, 1.0);
    double R = fast_rsqrt(1.0 - z);                     // shared by all branches
    if (mid) return (1.5707963267948966 - cd * A) * R;
    double AR = A * R;
    if (cd > 0.0) return AR;                            // 2A*rsqrt(4-4z) == A*R
    double Rz = fast_rsqrt(z);                          // z >= 5e-8 (clamp)
    return fma(1.5707963267948966 * Rz, R, -AR);        // (pi*Rz-2A)*R/2
}

// ===========================================================================
// Fused flow step: 4 nodes per wave, lane = c + 16*q; optional degree-sorted
// permutation of node processing order (bit-identical results, better balance)
// ===========================================================================
template <typename TI, typename TO>
__global__ void flow_kernel(const TI* __restrict__ x,
                            const int* __restrict__ rowptr,
                            const int2* __restrict__ edata,
                            const int* __restrict__ perm,
                            const float* __restrict__ t_sqrt,
                            const float* __restrict__ alpha_sqrt,
                            const float* __restrict__ beta_sqrt,
                            TO* __restrict__ xout) {
    int wave = threadIdx.x >> 6;                  // 4 waves / block
    int lane = threadIdx.x & 63;
    int q = lane >> 4;
    int c = lane & 15;
    int slot = (blockIdx.x * 4 + wave) * 4 + q;   // 16 nodes / block, exact
    int i = perm ? perm[slot] : slot;

    int beg = rowptr[i];
    int end = rowptr[i + 1];

    const TI* xi = x + ((size_t)i * N_CH + c) * DIM;
    double ax = (double)xi[0], ay = (double)xi[1], az = (double)xi[2];

    double sx = 0.0, sy = 0.0, sz = 0.0, sw = 0.0;
    for (int k = beg; k < end; ++k) {
        int2 ed = edata[k];
        int r = ed.x;
        double w = (double)__int_as_float(ed.y);
        const TI* xr = x + ((size_t)r * N_CH + c) * DIM;
        double bx = (double)xr[0], by = (double)xr[1], bz = (double)xr[2];

        double cd = ax * bx + ay * by + az * bz;
        cd = fmin(fmax(cd, -1.0 + 1e-7), 1.0 - 1e-7);
        double f = w * theta_over_sin(cd);

        sx += f * (bx - cd * ax);
        sy += f * (by - cd * ay);
        sz += f * (bz - cd * az);
        sw += w;
    }

    double dg = sw + 1e-12;
    double inv = 1.0 / dg;
    double vx = -sx * inv, vy = -sy * inv, vz = -sz * inv;

    double t = (double)t_sqrt[c];     t = (t * t) / (double)N_STEPS;
    double a = (double)alpha_sqrt[c]; a = a * a;
    double b = (double)beta_sqrt[c];  b = b * b;

    double nrm = sqrt(vx * vx + vy * vy + vz * vz + EPS_D);
    double d = 1.0 / (1.0 + exp(-b * (nrm - a)));
    double scale = (nrm * d <= 1.0) ? d : (1.0 / nrm);
    double fs = -scale * t;
    vx *= fs; vy *= fs; vz *= fs;

    double n = sqrt(vx * vx + vy * vy + vz * vz + 1e-16);
    double cn = cos(n);
    double sf = sin(n) / n;

    TO* xo = xout + ((size_t)i * N_CH + c) * DIM;
    xo[0] = (TO)(cn * ax + sf * vx);
    xo[1] = (TO)(cn * ay + sf * vy);
    xo[2] = (TO)(cn * az + sf * vz);
}

// ===========================================================================
// Fallback (round-1 fp32 atomic path, which passed) if d_ws too small
// ===========================================================================
__global__ void deg_kernel(const int* __restrict__ senders,
                           const float* __restrict__ weights,
                           float* __restrict__ deg) {
    int e = blockIdx.x * blockDim.x + threadIdx.x;
    if (e < N_EDGES) atomicAdd(&deg[senders[e]], weights[e]);
}

__global__ void edge_kernel(const float* __restrict__ x,
                            const int* __restrict__ senders,
                            const int* __restrict__ receivers,
                            const float* __restrict__ weights,
                            float* __restrict__ agg) {
    unsigned int tid = blockIdx.x * blockDim.x + threadIdx.x;
    if (tid >= (unsigned int)N_EDGES * N_CH) return;
    unsigned int e = tid >> 4;
    unsigned int c = tid & 15u;
    int s = senders[e];
    int r = receivers[e];
    float w = weights[e];
    const float* xs = x + ((size_t)s * N_CH + c) * DIM;
    const float* xr = x + ((size_t)r * N_CH + c) * DIM;
    float ax = xs[0], ay = xs[1], az = xs[2];
    float bx = xr[0], by = xr[1], bz = xr[2];
    float cd = ax * bx + ay * by + az * bz;
    cd = fminf(fmaxf(cd, -1.0f + 1e-7f), 1.0f - 1e-7f);
    float theta = acosf(cd);
    float sn = sqrtf(fmaxf(1.0f - cd * cd, 0.0f));
    float f = w * theta / sn;
    float* ag = agg + ((size_t)s * N_CH + c) * DIM;
    atomicAdd(&ag[0], f * (bx - cd * ax));
    atomicAdd(&ag[1], f * (by - cd * ay));
    atomicAdd(&ag[2], f * (bz - cd * az));
}

__global__ void node_kernel(const float* __restrict__ xin,
                            const float* __restrict__ agg,
                            const float* __restrict__ deg,
                            const float* __restrict__ t_sqrt,
                            const float* __restrict__ alpha_sqrt,
                            const float* __restrict__ beta_sqrt,
                            float* __restrict__ xout) {
    unsigned int tid = blockIdx.x * blockDim.x + threadIdx.x;
    if (tid >= (unsigned int)N_NODES * N_CH) return;
    unsigned int i = tid >> 4;
    unsigned int c = tid & 15u;
    float dg = deg[i] + 1e-12f;
    const float* ag = agg + (size_t)tid * DIM;
    float vx = -ag[0] / dg, vy = -ag[1] / dg, vz = -ag[2] / dg;
    float t = t_sqrt[c]; t = (t * t) * (1.0f / N_STEPS);
    float a = alpha_sqrt[c]; a = a * a;
    float b = beta_sqrt[c]; b = b * b;
    float nrm = sqrtf(vx * vx + vy * vy + vz * vz + 1.1920929e-7f);
    float d = 1.0f / (1.0f + __expf(-b * (nrm - a)));
    float scale = (nrm * d <= 1.0f) ? d : (1.0f / nrm);
    float fs = -scale * t;
    vx *= fs; vy *= fs; vz *= fs;
    const float* xi = xin + (size_t)tid * DIM;
    float axx = xi[0], ayy = xi[1], azz = xi[2];
    float n = sqrtf(vx * vx + vy * vy + vz * vz + 1e-16f);
    float cn = cosf(n);
    float sf = sinf(n) / n;
    float* xo = xout + (size_t)tid * DIM;
    xo[0] = cn * axx + sf * vx;
    xo[1] = cn * ayy + sf * vy;
    xo[2] = cn * azz + sf * vz;
}

extern "C" void kernel_launch(void* const* d_in, const int* in_sizes, int n_in,
                              void* d_out, int out_size, void* d_ws, size_t ws_size,
                              hipStream_t stream) {
    const float* nodes      = (const float*)d_in[0];
    const int*   senders    = (const int*)d_in[1];
    const int*   receivers  = (const int*)d_in[2];
    const float* weights    = (const float*)d_in[3];
    const float* t_sqrt     = (const float*)d_in[4];
    const float* alpha_sqrt = (const float*)d_in[5];
    const float* beta_sqrt  = (const float*)d_in[6];
    float* out = (float*)d_out;

    const size_t AL = 255;
    const size_t xtmp_b   = (size_t)N_NODES * N_CH * DIM * sizeof(double);   // 38.4 MB
    const size_t rowptr_b = (((size_t)(N_NODES + 1) * sizeof(int)) + AL) & ~AL;
    const size_t cnt_b    = (((size_t)N_NODES * sizeof(int)) + AL) & ~AL;
    const size_t bins_b   = 1024;   // bins|binoff|binfill|pad (4*64*4 rounded)
    const size_t part_b   = 4096;
    const size_t perm_b   = (((size_t)N_NODES * sizeof(int)) + AL) & ~AL;
    const size_t edata_b  = (size_t)N_EDGES * sizeof(int2);                  // 12.8 MB
    const size_t need_sorted = xtmp_b + rowptr_b + cnt_b + bins_b + part_b + perm_b + edata_b;
    const size_t need_plain  = xtmp_b + rowptr_b + cnt_b + bins_b + part_b + edata_b;

    if (ws_size >= need_plain) {
        bool sorted = (ws_size >= need_sorted);
        char* p = (char*)d_ws;
        double* xtmp  = (double*)p;           p += xtmp_b;
        int*   rowptr = (int*)p;              p += rowptr_b;
        int*   cnt    = (int*)p;              p += cnt_b;
        int*   bins   = (int*)p;              // [0..63] counts
        int*   binoff = bins + 64;
        int*   binfill= bins + 128;           p += bins_b;
        int*   part   = (int*)p;              p += part_b;
        int*   perm   = nullptr;
        if (sorted) { perm = (int*)p;         p += perm_b; }
        int2*  edata  = (int2*)p;

        // zero cnt + bins in one memset (adjacent)
        hipMemsetAsync(cnt, 0, cnt_b + 256, stream);
        hist_kernel<<<(N_EDGES / 4 + 255) / 256, 256, 0, stream>>>(
            (const int4*)senders, cnt);
        scan_partials<<<NBLK, PB, 0, stream>>>(cnt, part);
        scan_mid<<<1, 128, 0, stream>>>(part, rowptr);
        scan_apply<<<NBLK, PB, 0, stream>>>(cnt, part, rowptr);
        if (sorted) {
            dsort_hist<<<NBLK, PB, 0, stream>>>(cnt, bins);
            dsort_scan<<<1, 64, 0, stream>>>(bins, binoff, binfill);
            dsort_scatter<<<NBLK, PB, 0, stream>>>(cnt, binoff, binfill, perm);
        }
        // consumes cnt (decrements to zero)
        scatter_kernel<<<(N_EDGES + 255) / 256, 256, 0, stream>>>(
            senders, receivers, weights, rowptr, cnt, edata);

        int grid = N_NODES / 16;   // 6250, exact
        flow_kernel<float, double><<<grid, 256, 0, stream>>>(
            nodes, rowptr, edata, perm, t_sqrt, alpha_sqrt, beta_sqrt, xtmp);
        flow_kernel<double, float><<<grid, 256, 0, stream>>>(
            xtmp, rowptr, edata, perm, t_sqrt, alpha_sqrt, beta_sqrt, out);
    } else {
        // fallback: round-1 fp32 atomic-scatter path (passed at 1.3e-2)
        float* agg = (float*)d_ws;
        float* deg = agg + (size_t)N_NODES * N_CH * DIM;
        hipMemsetAsync(deg, 0, N_NODES * sizeof(float), stream);
        deg_kernel<<<(N_EDGES + 255) / 256, 256, 0, stream>>>(senders, weights, deg);
        const float* xin = nodes;
        for (int step = 0; step < N_STEPS; ++step) {
            hipMemsetAsync(agg, 0, (size_t)N_NODES * N_CH * DIM * sizeof(float), stream);
            unsigned int n_ec = (unsigned int)N_EDGES * N_CH;
            edge_kernel<<<(n_ec + 255) / 256, 256, 0, stream>>>(xin, senders, receivers,
                                                                weights, agg);
            unsigned int n_nc = (unsigned int)N_NODES * N_CH;
            node_kernel<<<(n_nc + 255) / 256, 256, 0, stream>>>(xin, agg, deg, t_sqrt,
                                                                alpha_sqrt, beta_sqrt, out);
            xin = out;
        }
    }
}